// Round 8
// baseline (166.612 us; speedup 1.0000x reference)
//
#include <hip/hip_runtime.h>
#include <hip/hip_bf16.h>
#include <stdint.h>

#define D_DIM 1024
#define B_DIM 8
#define S_DIM 1024

typedef __bf16 bf16;
typedef __bf16 bf16x4 __attribute__((ext_vector_type(4)));
typedef __bf16 bf16x8 __attribute__((ext_vector_type(8)));
typedef float floatx4 __attribute__((ext_vector_type(4)));

__device__ __forceinline__ void async_copy16(const void* g, void* l) {
    __builtin_amdgcn_global_load_lds(
        (const __attribute__((address_space(1))) void*)g,
        (__attribute__((address_space(3))) void*)l, 16, 0, 0);
}

// ---------------------------------------------------------------------------
// prep_du: cast dep fp32->bf16 (+ s_dep projection) and U fp32->bf16.
// blocks [0,1024): dep rows, 2 rows per wave. blocks [1024,1280): U rows.
// ---------------------------------------------------------------------------
__global__ __launch_bounds__(256) void prep_du(
    const float* __restrict__ dep, const float* __restrict__ U,
    const float* __restrict__ edge_W,
    bf16* __restrict__ dep_b, bf16* __restrict__ U_b,
    float* __restrict__ s_dep)
{
    int blk  = blockIdx.x;
    int wid  = threadIdx.x >> 6;
    int lane = threadIdx.x & 63;

    if (blk < 1024) {
        const float* w2 = edge_W + D_DIM;
        #pragma unroll
        for (int rep = 0; rep < 2; ++rep) {
            int r = blk * 8 + wid * 2 + rep;     // 0..8191
            const float* src = dep   + (size_t)r * D_DIM;
            bf16*        dst = dep_b + (size_t)r * D_DIM;
            float d = 0.0f;
            #pragma unroll
            for (int it = 0; it < 4; ++it) {
                int idx = it * 64 + lane;
                float4 v  = ((const float4*)src)[idx];
                float4 wv = ((const float4*)w2)[idx];
                bf16x4 o;
                o[0] = (bf16)v.x; o[1] = (bf16)v.y; o[2] = (bf16)v.z; o[3] = (bf16)v.w;
                ((bf16x4*)dst)[idx] = o;
                d += v.x * wv.x + v.y * wv.y + v.z * wv.z + v.w * wv.w;
            }
            #pragma unroll
            for (int off = 32; off > 0; off >>= 1)
                d += __shfl_down(d, off, 64);
            if (lane == 0) s_dep[r] = d;
        }
    } else {
        int row = (blk - 1024) * 4 + wid;        // 0..1023
        const float* src = U   + (size_t)row * D_DIM;
        bf16*        dst = U_b + (size_t)row * D_DIM;
        #pragma unroll
        for (int it = 0; it < 4; ++it) {
            int idx = it * 64 + lane;
            float4 v = ((const float4*)src)[idx];
            bf16x4 o;
            o[0] = (bf16)v.x; o[1] = (bf16)v.y; o[2] = (bf16)v.z; o[3] = (bf16)v.w;
            ((bf16x4*)dst)[idx] = o;
        }
    }
}

// ---------------------------------------------------------------------------
// 64x128 GEMM core (R7 occupancy fix): C = A[64xK] * Bt[128xK]^T tile,
// BK=64, 256 threads = 4 waves as 1M x 4N (per-wave 64x32 = acc[4][2] —
// identical fragment math / XOR swizzle / conflict-free reads as the
// verified 128x128 core; wr pinned to 0). LDS 24 KB -> with 1024-block
// grids this gives 4 blocks/CU = 4 independent barrier domains and 16
// waves/CU (vs 2 domains at R7's 512-block config, Occupancy 25%).
// ---------------------------------------------------------------------------
__device__ __forceinline__ void gemm_core64(
    const bf16* __restrict__ Ab, const bf16* __restrict__ Bb,
    bf16* As, bf16* Bs, floatx4 (&acc)[4][2],
    int tid, int wid, int lane, int quad, int l16, int wc)
{
    for (int k0 = 0; k0 < D_DIM; k0 += 64) {
        // ---- stage A (64x64: 512 granules, 2/thread) ----
        #pragma unroll
        for (int it = 0; it < 2; ++it) {
            int g  = it * 256 + tid;
            int r  = g >> 3;
            int cg = (g & 7) ^ (r & 7);              // XOR swizzle
            int ldsoff = (it * 256 + wid * 64) * 8;  // wave-uniform base
            async_copy16(Ab + (size_t)r * D_DIM + k0 + cg * 8, &As[ldsoff]);
        }
        // ---- stage B (128x64: 1024 granules, 4/thread) ----
        #pragma unroll
        for (int it = 0; it < 4; ++it) {
            int g  = it * 256 + tid;
            int r  = g >> 3;
            int cg = (g & 7) ^ (r & 7);
            int ldsoff = (it * 256 + wid * 64) * 8;
            async_copy16(Bb + (size_t)r * D_DIM + k0 + cg * 8, &Bs[ldsoff]);
        }
        __syncthreads();   // staging complete

        #pragma unroll
        for (int kk = 0; kk < 64; kk += 32) {
            bf16x8 a[4], b[2];
            #pragma unroll
            for (int mt = 0; mt < 4; ++mt) {
                int row  = mt * 16 + l16;
                int slot = ((kk >> 3) + quad) ^ (row & 7);
                a[mt] = *(const bf16x8*)&As[row * 64 + slot * 8];
            }
            #pragma unroll
            for (int nt = 0; nt < 2; ++nt) {
                int row  = wc * 32 + nt * 16 + l16;
                int slot = ((kk >> 3) + quad) ^ (row & 7);
                b[nt] = *(const bf16x8*)&Bs[row * 64 + slot * 8];
            }
            __builtin_amdgcn_s_setprio(1);
            #pragma unroll
            for (int mt = 0; mt < 4; ++mt)
                #pragma unroll
                for (int nt = 0; nt < 2; ++nt)
                    acc[mt][nt] = __builtin_amdgcn_mfma_f32_16x16x32_bf16(
                        a[mt], b[nt], acc[mt][nt], 0, 0, 0);
            __builtin_amdgcn_s_setprio(0);
        }
        __syncthreads();   // all reads done before next-iter staging
    }
}

// ---------------------------------------------------------------------------
// K1 launch (2048 blocks, ROLE-INTERLEAVED 1:1):
//   lin even -> GEMM1 block g = lin/2 (1024): tmpD tile (64x128),
//       decode bx = g&7 (U N-tile), by = g>>3 (dep M-tile, 0..127).
//   lin odd  -> head-cast block c = lin/2 (1024): cast head fp32->bf16 +
//       s_head projection, 2 rows/wave (8 rows/block).
// Interleave keeps fast-retiring cast blocks flowing through the
// latency-bound GEMM stream (R6 lesson: ordered roles serialize).
// ---------------------------------------------------------------------------
__global__ __launch_bounds__(256) void gemm1_kernel(
    const bf16* __restrict__ dep_b, const bf16* __restrict__ U_b,
    bf16* __restrict__ tmpD,
    const float* __restrict__ head, const float* __restrict__ edge_W,
    bf16* __restrict__ head_b, float* __restrict__ s_head)
{
    int tid  = threadIdx.x;
    int wid  = tid >> 6;
    int lane = tid & 63;
    int lin  = blockIdx.x;

    if (lin & 1) {
        // ---- head cast + projection ----
        int c = lin >> 1;                             // 0..1023
        const float* w1 = edge_W;
        #pragma unroll
        for (int rep = 0; rep < 2; ++rep) {
            int row = c * 8 + wid * 2 + rep;          // 0..8191
            const float* src = head   + (size_t)row * D_DIM;
            bf16*        dst = head_b + (size_t)row * D_DIM;
            float d = 0.0f;
            #pragma unroll
            for (int it = 0; it < 4; ++it) {
                int idx = it * 64 + lane;
                float4 v  = ((const float4*)src)[idx];
                float4 wv = ((const float4*)w1)[idx];
                bf16x4 o;
                o[0] = (bf16)v.x; o[1] = (bf16)v.y; o[2] = (bf16)v.z; o[3] = (bf16)v.w;
                ((bf16x4*)dst)[idx] = o;
                d += v.x * wv.x + v.y * wv.y + v.z * wv.z + v.w * wv.w;
            }
            #pragma unroll
            for (int off = 32; off > 0; off >>= 1)
                d += __shfl_down(d, off, 64);
            if (lane == 0) s_head[row] = d;
        }
        return;
    }

    // ---- GEMM1 (64x128 tile) ----
    __shared__ bf16 As[64 * 64];
    __shared__ bf16 Bs[128 * 64];

    int quad = lane >> 4;
    int l16  = lane & 15;
    int wc   = wid;        // 0..3 -> 32-col strip

    int g  = lin >> 1;     // 0..1023
    int bx = g & 7;        // N-tile (U rows)
    int by = g >> 3;       // M-tile (dep rows, 0..127)

    int tile_m = by * 64;
    int tile_n = bx * 128;
    const bf16* Ab = dep_b + (size_t)tile_m * D_DIM;
    const bf16* Bb = U_b   + (size_t)tile_n * D_DIM;

    floatx4 zero = {0.0f, 0.0f, 0.0f, 0.0f};
    floatx4 acc[4][2];
    #pragma unroll
    for (int i = 0; i < 4; ++i)
        #pragma unroll
        for (int j = 0; j < 2; ++j) acc[i][j] = zero;

    gemm_core64(Ab, Bb, As, Bs, acc, tid, wid, lane, quad, l16, wc);

    int col0 = tile_n + wc * 32;
    #pragma unroll
    for (int mt = 0; mt < 4; ++mt)
        #pragma unroll
        for (int r = 0; r < 4; ++r) {
            int row = tile_m + mt * 16 + quad * 4 + r;
            #pragma unroll
            for (int nt = 0; nt < 2; ++nt) {
                int col = col0 + nt * 16 + l16;
                tmpD[(size_t)row * D_DIM + col] = (bf16)acc[mt][nt][r];
            }
        }
}

// ---------------------------------------------------------------------------
// K2: out = head_b @ tmpD^T + s_head + s_dep + bias. 1024 blocks (64x128
// tiles): 16 M-tiles x 8 N-tiles x 8 batches. XCD-chunk decode keeps batch
// bz on XCD bz (head_b/tmpD 4 MB = its L2).
// ---------------------------------------------------------------------------
__global__ __launch_bounds__(256) void gemm2_kernel(
    const bf16* __restrict__ head_b, const bf16* __restrict__ tmpD,
    float* __restrict__ out,
    const float* __restrict__ s_head, const float* __restrict__ s_dep,
    const float* __restrict__ edge_b)
{
    __shared__ bf16 As[64 * 64];
    __shared__ bf16 Bs[128 * 64];

    int tid  = threadIdx.x;
    int wid  = tid >> 6;
    int lane = tid & 63;
    int quad = lane >> 4;
    int l16  = lane & 15;
    int wc   = wid;        // 0..3

    int lin = blockIdx.x;                      // 0..1023
    int swz = (lin & 7) * 128 + (lin >> 3);    // bijective XCD-chunk
    int bx  = swz & 7;          // tmpD j-tile
    int by  = (swz >> 3) & 15;  // head i-tile (0..15)
    int bz  = swz >> 7;         // batch (aligned with XCD = lin&7)

    int tile_m = by * 64;
    int tile_n = bx * 128;
    const bf16* Ab = head_b + (size_t)bz * S_DIM * D_DIM + (size_t)tile_m * D_DIM;
    const bf16* Bb = tmpD   + (size_t)bz * S_DIM * D_DIM + (size_t)tile_n * D_DIM;

    floatx4 zero = {0.0f, 0.0f, 0.0f, 0.0f};
    floatx4 acc[4][2];
    #pragma unroll
    for (int i = 0; i < 4; ++i)
        #pragma unroll
        for (int j = 0; j < 2; ++j) acc[i][j] = zero;

    gemm_core64(Ab, Bb, As, Bs, acc, tid, wid, lane, quad, l16, wc);

    float b0 = edge_b[0];
    const float* srow = s_head + (size_t)bz * S_DIM;
    const float* scol = s_dep  + (size_t)bz * S_DIM;
    float* Cf = out + (size_t)bz * S_DIM * S_DIM;
    int col0 = tile_n + wc * 32;
    #pragma unroll
    for (int mt = 0; mt < 4; ++mt)
        #pragma unroll
        for (int r = 0; r < 4; ++r) {
            int row = tile_m + mt * 16 + quad * 4 + r;
            float sh = srow[row] + b0;
            #pragma unroll
            for (int nt = 0; nt < 2; ++nt) {
                int col = col0 + nt * 16 + l16;
                __builtin_nontemporal_store(acc[mt][nt][r] + sh + scol[col],
                                            &Cf[(size_t)row * S_DIM + col]);
            }
        }
}

// ---------------------------------------------------------------------------
// Chain (3 dispatches):
//   1. prep_du:  dep_b, U_b, s_dep                         (~10 us)
//   2. gemm1:    tmpD (1024 blocks) interleaved with head cast (1024)
//   3. gemm2:    out (1024 blocks)
// ---------------------------------------------------------------------------
extern "C" void kernel_launch(void* const* d_in, const int* in_sizes, int n_in,
                              void* d_out, int out_size, void* d_ws, size_t ws_size,
                              hipStream_t stream) {
    const float* head   = (const float*)d_in[0];
    const float* dep    = (const float*)d_in[1];
    const float* edge_U = (const float*)d_in[2];
    const float* edge_W = (const float*)d_in[3];
    const float* edge_b = (const float*)d_in[4];
    float* out = (float*)d_out;

    char* ws = (char*)d_ws;
    const size_t nBSD = (size_t)B_DIM * S_DIM * D_DIM;

    bf16*  head_b = (bf16*)ws;  ws += nBSD * sizeof(bf16);
    bf16*  dep_b  = (bf16*)ws;  ws += nBSD * sizeof(bf16);
    bf16*  U_b    = (bf16*)ws;  ws += (size_t)D_DIM * D_DIM * sizeof(bf16);
    bf16*  tmpD   = (bf16*)ws;  ws += nBSD * sizeof(bf16);
    float* s_head = (float*)ws; ws += (size_t)B_DIM * S_DIM * sizeof(float);
    float* s_dep  = (float*)ws; ws += (size_t)B_DIM * S_DIM * sizeof(float);

    // 1. cast dep + U, s_dep projection (only what GEMM1 needs)
    prep_du<<<1024 + 256, 256, 0, stream>>>(
        dep, edge_U, edge_W, dep_b, U_b, s_dep);

    // 2. GEMM1 (1024 blocks) interleaved 1:1 with head cast (1024 blocks)
    gemm1_kernel<<<2048, 256, 0, stream>>>(
        dep_b, U_b, tmpD, head, edge_W, head_b, s_head);

    // 3. GEMM2 (1024 blocks)
    gemm2_kernel<<<1024, 256, 0, stream>>>(
        head_b, tmpD, out, s_head, s_dep, edge_b);
}

// Round 9
// 154.526 us; speedup vs baseline: 1.0782x; 1.0782x over previous
//
#include <hip/hip_runtime.h>
#include <hip/hip_bf16.h>
#include <stdint.h>

#define D_DIM 1024
#define B_DIM 8
#define S_DIM 1024

typedef __bf16 bf16;
typedef __bf16 bf16x4 __attribute__((ext_vector_type(4)));
typedef __bf16 bf16x8 __attribute__((ext_vector_type(8)));
typedef float floatx4 __attribute__((ext_vector_type(4)));

__device__ __forceinline__ void async_copy16(const void* g, void* l) {
    __builtin_amdgcn_global_load_lds(
        (const __attribute__((address_space(1))) void*)g,
        (__attribute__((address_space(3))) void*)l, 16, 0, 0);
}

// barrier + compile-time fence: stops hipcc hoisting register-only MFMA
// above the s_barrier (rule #18) and pins the phase structure.
#define SBAR() do { asm volatile("s_barrier" ::: "memory"); \
                    __builtin_amdgcn_sched_barrier(0); } while (0)

// ---------------------------------------------------------------------------
// Session-best configuration (Round 3, 155.7 us measured; session entry was
// 163.0). Budget model fitted across R3-R8:
//   dur ≈ 43 us harness workspace fill (fixed) + ~85 us kernel sum
//       + ~27 us dispatch gaps (fixed per launch).
// Attempts that regressed and were reverted: coarse dbuf (R2 +4), reg-staged
// prep fusion (R4 +40), grid-barrier GEMM fusion (R5 +66), cast/GEMM
// role-interleave (R6/R7 +3/+9), small-tile occupancy doubling (R8 +11).
// ---------------------------------------------------------------------------

// ---------------------------------------------------------------------------
// Prep kernel (fused): blocks [0,4096) cast head/dep fp32->bf16 + W-projection
// (one wave per row); blocks [4096,4352) cast U fp32->bf16 (no transpose —
// GEMM chain ordered so U is consumed row-major as Bt directly).
// ---------------------------------------------------------------------------
__global__ __launch_bounds__(256) void prep_kernel(
    const float* __restrict__ head, const float* __restrict__ dep,
    const float* __restrict__ U, const float* __restrict__ edge_W,
    bf16* __restrict__ head_b, bf16* __restrict__ dep_b,
    bf16* __restrict__ U_b,
    float* __restrict__ s_head, float* __restrict__ s_dep)
{
    int blk  = blockIdx.x;
    int wid  = threadIdx.x >> 6;
    int lane = threadIdx.x & 63;

    if (blk < 4096) {
        int row = blk * 4 + wid;

        const float* src;
        bf16* dst;
        const float* w;
        float* sout;
        if (row < B_DIM * S_DIM) {
            src  = head   + (size_t)row * D_DIM;
            dst  = head_b + (size_t)row * D_DIM;
            w    = edge_W;
            sout = s_head + row;
        } else {
            int r = row - B_DIM * S_DIM;
            src  = dep   + (size_t)r * D_DIM;
            dst  = dep_b + (size_t)r * D_DIM;
            w    = edge_W + D_DIM;
            sout = s_dep + r;
        }
        float d = 0.0f;
        #pragma unroll
        for (int it = 0; it < 4; ++it) {
            int idx = it * 64 + lane;
            float4 v  = ((const float4*)src)[idx];
            float4 wv = ((const float4*)w)[idx];
            bf16x4 o;
            o[0] = (bf16)v.x; o[1] = (bf16)v.y; o[2] = (bf16)v.z; o[3] = (bf16)v.w;
            ((bf16x4*)dst)[idx] = o;
            d += v.x * wv.x + v.y * wv.y + v.z * wv.z + v.w * wv.w;
        }
        #pragma unroll
        for (int off = 32; off > 0; off >>= 1)
            d += __shfl_down(d, off, 64);
        if (lane == 0) *sout = d;
    } else {
        int row = (blk - 4096) * 4 + wid;
        const float* src = U   + (size_t)row * D_DIM;
        bf16*        dst = U_b + (size_t)row * D_DIM;
        #pragma unroll
        for (int it = 0; it < 4; ++it) {
            int idx = it * 64 + lane;
            float4 v = ((const float4*)src)[idx];
            bf16x4 o;
            o[0] = (bf16)v.x; o[1] = (bf16)v.y; o[2] = (bf16)v.z; o[3] = (bf16)v.w;
            ((bf16x4*)dst)[idx] = o;
        }
    }
}

// ---------------------------------------------------------------------------
// Stage HALF of one K-tile (2 of 4 A-loads + 1 of 2 B-loads per thread).
// XOR-swizzled source columns, linear LDS dest: LDS[r][p] = G[r][p ^ (r&7)]
// (granules of 8 bf16). half in {0,1}.
// ---------------------------------------------------------------------------
__device__ __forceinline__ void stage_half(
    const bf16* __restrict__ Ab, const bf16* __restrict__ Bb,
    bf16* As, bf16* Bs, int k0, int wid, int lane, int half)
{
    #pragma unroll
    for (int it = 0; it < 2; ++it) {
        int ii = half * 2 + it;
        int g  = wid * 256 + ii * 64 + lane;
        int r  = g >> 3;
        int cg = (g & 7) ^ (r & 7);
        int ldsoff = (wid * 256 + ii * 64) * 8;   // wave-uniform
        async_copy16(Ab + (size_t)r * D_DIM + k0 + cg * 8, &As[ldsoff]);
    }
    {
        int gb  = wid * 128 + half * 64 + lane;
        int rb  = gb >> 3;
        int cgb = (gb & 7) ^ (rb & 7);
        int ldsoffb = (wid * 128 + half * 64) * 8;
        async_copy16(Bb + (size_t)rb * D_DIM + k0 + cgb * 8, &Bs[ldsoffb]);
    }
}

__device__ __forceinline__ void phase_reads(
    const bf16* As, const bf16* Bs, int kk,
    int wr, int wc, int quad, int l16,
    bf16x8 a[4], bf16x8 b[4])
{
    #pragma unroll
    for (int mt = 0; mt < 4; ++mt) {
        int row  = wr * 64 + mt * 16 + l16;
        int slot = ((kk >> 3) + quad) ^ (row & 7);
        a[mt] = *(const bf16x8*)&As[row * 64 + slot * 8];
    }
    #pragma unroll
    for (int nt = 0; nt < 4; ++nt) {
        int row  = wc * 64 + nt * 16 + l16;
        int slot = ((kk >> 3) + quad) ^ (row & 7);
        b[nt] = *(const bf16x8*)&Bs[row * 64 + slot * 8];
    }
}

__device__ __forceinline__ void phase_fma(
    const bf16x8 a[4], const bf16x8 b[4], floatx4 acc[4][4])
{
    __builtin_amdgcn_s_setprio(1);
    #pragma unroll
    for (int mt = 0; mt < 4; ++mt)
        #pragma unroll
        for (int nt = 0; nt < 4; ++nt)
            acc[mt][nt] = __builtin_amdgcn_mfma_f32_16x16x32_bf16(
                a[mt], b[nt], acc[mt][nt], 0, 0, 0);
    __builtin_amdgcn_s_setprio(0);
}

// ---------------------------------------------------------------------------
// GEMM: C[m][n] = sum_k A[m][k] * Bt[n][k], K = 1024.
// BM=256 x BN=128, BK=64, 512 threads = 8 waves as 4M x 2N (per-wave 64x64,
// acc[4][4]). Triple-buffered LDS (3 x 48 KB), prefetch depth 2: tile t+2's
// 6 loads issued 3-per-phase during tile t. Boundary: s_waitcnt vmcnt(6)
// (t+1's loads stay in flight) + s_barrier. Per phase: 8 ds_read -> 3
// global_load_lds -> SBAR -> setprio(1) 16 MFMA setprio(0).
// Grid = 256 blocks = 1/CU both launches; bijective XCD-chunk swizzle gives
// each XCD a 4 MB (=L2) working set.
// EPI=0: store bf16.  EPI=1: fp32 + s_row[m] + s_col[n] + bias, nontemporal.
// ---------------------------------------------------------------------------
template <int EPI>
__global__ __launch_bounds__(512, 2) void gemm_bt_kernel(
    const bf16* __restrict__ A, const bf16* __restrict__ Bt,
    void* __restrict__ Cout,
    int N,
    long long sA, long long sB, long long sC,
    const float* __restrict__ s_row, const float* __restrict__ s_col,
    const float* __restrict__ bias)
{
    // per tile-buffer: A 256*64 (32 KB) + B 128*64 (16 KB) = 24576 elems
    __shared__ bf16 lds[3 * 24576];   // 144 KB

    int tid  = threadIdx.x;
    int wid  = tid >> 6;       // 0..7
    int lane = tid & 63;
    int quad = lane >> 4;
    int l16  = lane & 15;
    int wr   = wid & 3;        // 0..3 -> 64-row strip
    int wc   = wid >> 2;       // 0..1 -> 64-col strip

    // ---- XCD-chunk swizzle (bijective: nwg = 256, 256 % 8 == 0) ----
    int nx  = gridDim.x, ny = gridDim.y;
    int lin = blockIdx.x + nx * (blockIdx.y + ny * blockIdx.z);
    int nwg = nx * ny * gridDim.z;
    int swz = (lin & 7) * (nwg >> 3) + (lin >> 3);
    int bx  = swz % nx;
    int rem = swz / nx;
    int by  = rem % ny;
    int bz  = rem / ny;

    int tile_m = by * 256;
    int tile_n = bx * 128;

    const bf16* Ab = A  + (size_t)bz * sA + (size_t)tile_m * D_DIM;
    const bf16* Bb = Bt + (size_t)bz * sB + (size_t)tile_n * D_DIM;

    floatx4 zero = {0.0f, 0.0f, 0.0f, 0.0f};
    floatx4 acc[4][4];
    #pragma unroll
    for (int i = 0; i < 4; ++i)
        #pragma unroll
        for (int j = 0; j < 4; ++j) acc[i][j] = zero;

    const int NT = D_DIM / 64;   // 16 K-tiles

    // prologue: stage tile 0 -> buf0, tile 1 -> buf1 (12 loads in flight)
    stage_half(Ab, Bb, lds, lds + 16384, 0, wid, lane, 0);
    stage_half(Ab, Bb, lds, lds + 16384, 0, wid, lane, 1);
    stage_half(Ab, Bb, lds + 24576, lds + 24576 + 16384, 64, wid, lane, 0);
    stage_half(Ab, Bb, lds + 24576, lds + 24576 + 16384, 64, wid, lane, 1);

    for (int t = 0; t < NT; ++t) {
        bf16* As  = lds + (t % 3) * 24576;
        bf16* Bs  = As + 16384;
        bf16* Asn = lds + ((t + 2) % 3) * 24576;
        bf16* Bsn = Asn + 16384;
        bool pf   = (t + 2 < NT);

        // boundary: own 6 loads of tile t drained (t+1's 6 stay in flight),
        // then barrier => every wave's loads landed => slab complete.
        if (t < NT - 1) asm volatile("s_waitcnt vmcnt(6)" ::: "memory");
        else            asm volatile("s_waitcnt vmcnt(0)" ::: "memory");
        SBAR();

        // ---- phase 0 (kk = 0) ----
        {
            bf16x8 a[4], b[4];
            phase_reads(As, Bs, 0, wr, wc, quad, l16, a, b);
            if (pf) stage_half(Ab, Bb, Asn, Bsn, (t + 2) * 64, wid, lane, 0);
            SBAR();
            phase_fma(a, b, acc);
        }
        // ---- phase 1 (kk = 32) ----
        {
            bf16x8 a[4], b[4];
            phase_reads(As, Bs, 32, wr, wc, quad, l16, a, b);
            if (pf) stage_half(Ab, Bb, Asn, Bsn, (t + 2) * 64, wid, lane, 1);
            SBAR();
            phase_fma(a, b, acc);
        }
    }

    // ---- epilogue: C/D layout col = lane&15, row = quad*4 + reg ----
    int row0 = tile_m + wr * 64;
    int col0 = tile_n + wc * 64;
    if (EPI == 0) {
        bf16* Cb = (bf16*)Cout + (size_t)bz * sC;
        #pragma unroll
        for (int mt = 0; mt < 4; ++mt)
            #pragma unroll
            for (int r = 0; r < 4; ++r) {
                int row = row0 + mt * 16 + quad * 4 + r;
                #pragma unroll
                for (int nt = 0; nt < 4; ++nt) {
                    int col = col0 + nt * 16 + l16;
                    Cb[(size_t)row * N + col] = (bf16)acc[mt][nt][r];
                }
            }
    } else {
        float* Cf = (float*)Cout + (size_t)bz * sC;
        float b0 = bias[0];
        const float* srow = s_row + (size_t)bz * S_DIM;
        const float* scol = s_col + (size_t)bz * S_DIM;
        #pragma unroll
        for (int mt = 0; mt < 4; ++mt)
            #pragma unroll
            for (int r = 0; r < 4; ++r) {
                int row = row0 + mt * 16 + quad * 4 + r;
                float sh = srow[row] + b0;
                #pragma unroll
                for (int nt = 0; nt < 4; ++nt) {
                    int col = col0 + nt * 16 + l16;
                    __builtin_nontemporal_store(acc[mt][nt][r] + sh + scol[col],
                                                &Cf[(size_t)row * N + col]);
                }
            }
    }
}

// ---------------------------------------------------------------------------
// Chain:
//   tmpD[b,j,d] = sum_k dep[b,j,k] * U[d,k]      (Bt = U row-major, as-is)
//   out[b,i,j]  = sum_d head[b,i,d] * tmpD[b,j,d] + s_head[i] + s_dep[j] + b
// ---------------------------------------------------------------------------
extern "C" void kernel_launch(void* const* d_in, const int* in_sizes, int n_in,
                              void* d_out, int out_size, void* d_ws, size_t ws_size,
                              hipStream_t stream) {
    const float* head   = (const float*)d_in[0];
    const float* dep    = (const float*)d_in[1];
    const float* edge_U = (const float*)d_in[2];
    const float* edge_W = (const float*)d_in[3];
    const float* edge_b = (const float*)d_in[4];
    float* out = (float*)d_out;

    char* ws = (char*)d_ws;
    const size_t nBSD = (size_t)B_DIM * S_DIM * D_DIM;

    bf16*  head_b = (bf16*)ws;  ws += nBSD * sizeof(bf16);
    bf16*  dep_b  = (bf16*)ws;  ws += nBSD * sizeof(bf16);
    bf16*  U_b    = (bf16*)ws;  ws += (size_t)D_DIM * D_DIM * sizeof(bf16);
    bf16*  tmpD   = (bf16*)ws;  ws += nBSD * sizeof(bf16);
    float* s_head = (float*)ws; ws += (size_t)B_DIM * S_DIM * sizeof(float);
    float* s_dep  = (float*)ws; ws += (size_t)B_DIM * S_DIM * sizeof(float);

    // 1. fused cast+projection (4096 blocks) and U-cast (256 blocks)
    prep_kernel<<<4096 + 256, 256, 0, stream>>>(
        head, dep, edge_U, edge_W, head_b, dep_b, U_b, s_head, s_dep);

    // 2. tmpD[b,j,d] = dep[b,j,:] @ U^T rows   (M=8192, N=1024; 8x32 grid)
    gemm_bt_kernel<0><<<dim3(D_DIM / 128, (B_DIM * S_DIM) / 256, 1), 512, 0, stream>>>(
        dep_b, U_b, tmpD, D_DIM,
        0, 0, 0, nullptr, nullptr, nullptr);

    // 3. out[b,i,j] = head[b,i,:] @ tmpD[b,j,:] + ...   (8x4x8 grid)
    gemm_bt_kernel<1><<<dim3(S_DIM / 128, S_DIM / 256, B_DIM), 512, 0, stream>>>(
        head_b, tmpD, out, S_DIM,
        (long long)S_DIM * D_DIM, (long long)S_DIM * D_DIM,
        (long long)S_DIM * S_DIM,
        s_head, s_dep, edge_b);
}